// Round 12
// baseline (560.182 us; speedup 1.0000x reference)
//
#include <hip/hip_runtime.h>
#include <stdint.h>

typedef __attribute__((ext_vector_type(8))) short short8;
typedef __attribute__((ext_vector_type(4))) float f32x4;
typedef __attribute__((ext_vector_type(4))) int i32x4;

#define DMODEL 768
#define HID    2048
#define MROWS  4096   // 2*2048 tokens

// B-spline constants: h = (4-(-4))/(16-3) = 8/13
#define KINVH  (13.0f/8.0f)
#define KNOT0  (-4.0f - 3.0f*(8.0f/13.0f))

__device__ __forceinline__ unsigned short f2bf(float f) {
  unsigned int u = __float_as_uint(f);
  unsigned int r = (u + 0x7FFFu + ((u >> 16) & 1u)) >> 16;
  return (unsigned short)r;
}

// ---- weight f32 -> bf16, packed in MFMA-fragment order ----
// dst 16B-unit layout: [cb=col/16][kt2=k/32][q=l>>4][c16=l&15]; a B-fragment
// load (fixed cb,kt2) is lane-linear: addr = base + lane*16B.
template<int DIN>
__global__ void __launch_bounds__(256) conv_pack(const float* __restrict__ src,
                                                 unsigned short* __restrict__ dst,
                                                 int total_waves) {
  constexpr int NK2 = DIN / 2;               // number of 32-wide k halves
  int gw = blockIdx.x * 4 + (threadIdx.x >> 6);
  if (gw >= total_waves) return;
  int l   = threadIdx.x & 63;
  int cb  = gw / NK2;
  int kt2 = gw % NK2;
  int c16 = l & 15, q = l >> 4;
  int col = cb * 16 + c16;
  const float* s = src + ((size_t)col * DIN + kt2 * 2 + (q >> 1)) * 16 + (q & 1) * 8;
  float4 v0 = *(const float4*)s;
  float4 v1 = *(const float4*)(s + 4);
  short8 o;
  o[0] = (short)f2bf(v0.x); o[1] = (short)f2bf(v0.y);
  o[2] = (short)f2bf(v0.z); o[3] = (short)f2bf(v0.w);
  o[4] = (short)f2bf(v1.x); o[5] = (short)f2bf(v1.y);
  o[6] = (short)f2bf(v1.z); o[7] = (short)f2bf(v1.w);
  unsigned short* d = dst + (((size_t)cb * NK2 + kt2) * 64 + q * 16 + c16) * 8;
  *(short8*)d = o;
}

// ---- split-K=2 reduce, in place: p[i] = p[i] + p[i+n4] ----
__global__ void __launch_bounds__(256) reduce2(float4* __restrict__ p, int n4) {
  int i = blockIdx.x * 256 + threadIdx.x;
  if (i >= n4) return;
  float4 a = p[i], b = p[i + n4];
  float4 r;
  r.x = a.x + b.x; r.y = a.y + b.y; r.z = a.z + b.z; r.w = a.w + b.w;
  p[i] = r;
}

// ---- split-K=4 reduce: out[i] = sum over 4 planes ----
__global__ void __launch_bounds__(256) reduce4(const float4* __restrict__ p,
                                               float4* __restrict__ out, int n4) {
  int i = blockIdx.x * 256 + threadIdx.x;
  if (i >= n4) return;
  float4 a = p[i], b = p[i + n4], c = p[i + 2 * n4], d = p[i + 3 * n4];
  float4 r;
  r.x = a.x + b.x + c.x + d.x;
  r.y = a.y + b.y + c.y + d.y;
  r.z = a.z + b.z + c.z + d.z;
  r.w = a.w + b.w + c.w + d.w;
  out[i] = r;
}

// ---- fused basis + GEMM: A dbuf in LDS (2x8KB), B dbuf in registers ----
// C[n,o] = sum_{d,k} basis(X[n,d])_k * Wb'[o,k]
// Tile: BM=64 x BN=256, BK=64. 4 waves in 1x4; wave tile 64x64 (FM=FN=4).
// ONE barrier per K-step: STEP(kt) reads A from smA[p], writes basis(kt+1)
// into smA[p^1]; the end-of-step __syncthreads provides both write-visibility
// and read-WAR. B(kt+1) is issued into the ALTERNATE register set right after
// the A-frag ds_reads -> ~300cy (basis+32 MFMA) in flight before the barrier
// drains it: exposed B latency ~0 (r11's chain stalled here).
// K unrolled by 2 (NKS even) so buffer parity is compile-time (rule #20).
template<int DIN, int DOUT, int SPLITK>
__global__ void __launch_bounds__(256, 2)
kan_gemm(const float* __restrict__ X, const unsigned short* __restrict__ Wb,
         float* __restrict__ Out) {
  constexpr int BM  = 64;
  constexpr int BN  = 256;
  constexpr int NK  = (DIN * 16) / 64;
  constexpr int NK2 = DIN / 2;
  constexpr int NKS = NK / SPLITK;          // 96 / 128: even
  constexpr int GX  = MROWS / BM;           // 64
  constexpr int GY  = DOUT / BN;
  constexpr int CPX = (GX * GY) / 8;        // blocks per XCD (nwg%8==0, bijective)
  __shared__ __align__(16) char smA[2][BM * 128];   // 2 x 8KB swizzled basis tiles

  const int tid  = threadIdx.x;
  const int lane = tid & 63;
  const int wid  = tid >> 6;

  // XCD-chunked remap
  const int d    = blockIdx.x + blockIdx.y * GX;
  const int lf   = (d & 7) * CPX + (d >> 3);
  const int brow = (lf % GX) * BM;
  const int bcol = (lf / GX) * BN;
  const int kt0  = blockIdx.z * NKS;
  const int kt1  = kt0 + NKS;

  f32x4 acc[4][4];
#pragma unroll
  for (int m = 0; m < 4; ++m)
#pragma unroll
    for (int n = 0; n < 4; ++n) acc[m][n] = (f32x4){0.f, 0.f, 0.f, 0.f};

  // A-fragment LDS addressing (constant per lane)
  int a_base[4], a_sw[4];
#pragma unroll
  for (int m = 0; m < 4; ++m) {
    int row   = m * 16 + (lane & 15);
    a_base[m] = row * 128 + ((lane >> 4) * 16);
    a_sw[m]   = (row & 7) << 4;
  }

  // B-fragment pointers (advance 1024 shorts per K-step after each issue)
  const unsigned short* bp[4];
#pragma unroll
  for (int n = 0; n < 4; ++n)
    bp[n] = Wb + ((size_t)(bcol / 16 + wid * 4 + n) * NK2 + (size_t)kt0 * 2) * 512
               + lane * 8;

  const int br_ = tid >> 2;        // basis row
  const int bd_ = tid & 3;         // basis d-col within the 4-col step
  const float* xrow = X + (size_t)(brow + br_) * DIN + bd_;

  auto BASIS = [&](float xv, char* smp) {
    float u  = (xv - KNOT0) * KINVH;
    float uf = floorf(u);
    int   jj = (int)uf;
    float t  = u - uf;
    float t2 = t * t, t3 = t2 * t;
    float p0 = (1.0f / 6.0f) * (1.0f - 3.0f * t + 3.0f * t2 - t3);
    float p1 = (1.0f / 6.0f) * (4.0f - 6.0f * t2 + 3.0f * t3);
    float p2 = (1.0f / 6.0f) * (1.0f + 3.0f * t + 3.0f * t2 - 3.0f * t3);
    float p3 = (1.0f / 6.0f) * t3;

    int base = br_ * 128 + bd_ * 32;
    int sw   = (br_ & 7) << 4;
    *(i32x4*)(smp + (base ^ sw))        = (i32x4){0, 0, 0, 0};
    *(i32x4*)(smp + ((base + 16) ^ sw)) = (i32x4){0, 0, 0, 0};
    unsigned short q0 = f2bf(p0), q1 = f2bf(p1), q2 = f2bf(p2), q3 = f2bf(p3);
    int k0 = jj - 3;
    if ((unsigned)(k0 + 0) < 16u) *(unsigned short*)(smp + ((base + (k0 + 0) * 2) ^ sw)) = q0;
    if ((unsigned)(k0 + 1) < 16u) *(unsigned short*)(smp + ((base + (k0 + 1) * 2) ^ sw)) = q1;
    if ((unsigned)(k0 + 2) < 16u) *(unsigned short*)(smp + ((base + (k0 + 2) * 2) ^ sw)) = q2;
    if ((unsigned)(k0 + 3) < 16u) *(unsigned short*)(smp + ((base + (k0 + 3) * 2) ^ sw)) = q3;
  };

  short8 bvE[2][4], bvO[2][4];

  // ---- prologue: B(kt0) -> bvE; A(kt0) -> smA[0]; xv = X(kt0+1)
#pragma unroll
  for (int n = 0; n < 4; ++n) {
    bvE[0][n] = *(const short8*)(bp[n]);
    bvE[1][n] = *(const short8*)(bp[n] + 512);
    bp[n] += 1024;                 // now points at B(kt0+1)
  }
  BASIS(xrow[(size_t)kt0 * 4], &smA[0][0]);
  float xv = xrow[(size_t)((kt0 + 1 < kt1) ? kt0 + 1 : kt0) * 4];
  __syncthreads();

  // one STEP: read A from smR, write A(kt+1) to smW, use bc, fill bn
  auto STEP = [&](int kt, const char* smR, char* smW,
                  short8 (&bc)[2][4], short8 (&bn)[2][4]) {
    const bool more = (kt + 1 < kt1);

    // A fragments for both kk halves (8 ds_read_b128, 2-way conflict = free)
    short8 a0[4], a1[4];
#pragma unroll
    for (int m = 0; m < 4; ++m) {
      a0[m] = *(const short8*)(smR + (a_base[m] ^ a_sw[m]));
      a1[m] = *(const short8*)(smR + ((a_base[m] + 64) ^ a_sw[m]));
    }

    // issue B(kt+1) into the alternate register set (lands by the barrier)
    if (more) {
#pragma unroll
      for (int n = 0; n < 4; ++n) {
        bn[0][n] = *(const short8*)(bp[n]);
        bn[1][n] = *(const short8*)(bp[n] + 512);
        bp[n] += 1024;
      }
    }

    // next X (consumed next step; latency spans the whole step)
    int ktn = (kt + 2 < kt1) ? kt + 2 : kt1 - 1;
    float xn = xrow[(size_t)ktn * 4];

    // basis(kt+1) into the other LDS buffer (no barrier needed: disjoint buf)
    if (more) BASIS(xv, smW);

    // 32 MFMA on current tile
#pragma unroll
    for (int m = 0; m < 4; ++m)
#pragma unroll
      for (int n = 0; n < 4; ++n)
        acc[m][n] = __builtin_amdgcn_mfma_f32_16x16x32_bf16(a0[m], bc[0][n], acc[m][n], 0, 0, 0);
#pragma unroll
    for (int m = 0; m < 4; ++m)
#pragma unroll
      for (int n = 0; n < 4; ++n)
        acc[m][n] = __builtin_amdgcn_mfma_f32_16x16x32_bf16(a1[m], bc[1][n], acc[m][n], 0, 0, 0);

    xv = xn;
    __syncthreads();   // A(kt+1) visible; reads of smR done; B(kt+1) drained
  };

  for (int kt = kt0; kt < kt1; kt += 2) {
    STEP(kt,     &smA[0][0], &smA[1][0], bvE, bvO);
    STEP(kt + 1, &smA[1][0], &smA[0][0], bvO, bvE);
  }

  // ---- epilogue: C/D layout col=lane&15, row=(lane>>4)*4+q
  float* outp = Out + (size_t)blockIdx.z * MROWS * DOUT;
#pragma unroll
  for (int m = 0; m < 4; ++m)
#pragma unroll
    for (int n = 0; n < 4; ++n)
#pragma unroll
      for (int q = 0; q < 4; ++q) {
        int grow = brow + m * 16 + (lane >> 4) * 4 + q;
        int gcol = bcol + wid * 64 + n * 16 + (lane & 15);
        outp[(size_t)grow * DOUT + gcol] = acc[m][n][q];
      }
}

extern "C" void kernel_launch(void* const* d_in, const int* in_sizes, int n_in,
                              void* d_out, int out_size, void* d_ws, size_t ws_size,
                              hipStream_t stream) {
  const float* x  = (const float*)d_in[0];   // (2,2048,768) f32 -> (4096,768)
  const float* w1 = (const float*)d_in[1];   // (2048,768,16) f32
  const float* w2 = (const float*)d_in[2];   // (768,2048,16) f32
  float* out = (float*)d_out;                // (4096,768) f32

  // ws timeline (128 MiB):
  //   [0, 48M)   : w1b' (phase 1), then w2b' (phase 2, after GEMM1)
  //   [48M, 80M) : GEMM1 partial plane 0 -> becomes h (f32) after reduce2
  //   [80M, 112M): GEMM1 partial plane 1 (dead after reduce2)
  //   [80M, 128M): GEMM2 partial planes 0..3 (overwrites plane 1)
  char* ws = (char*)d_ws;
  unsigned short* wgb   = (unsigned short*)ws;                  // 50,331,648 B
  float*          part1 = (float*)(ws + 50331648);              // 2 x 33,554,432 B
  float*          hbf   = part1;                                // alias: plane 0
  float*          part2 = (float*)(ws + 83886080);              // 4 x 12,582,912 B (end = 128MiB)

  // phase 1: layer 1
  {
    const int waves = (HID / 16) * (DMODEL / 2);   // 128 * 384 = 49152
    conv_pack<DMODEL><<<waves / 4, 256, 0, stream>>>(w1, wgb, waves);
  }
  kan_gemm<DMODEL, HID, 2>
      <<<dim3(MROWS / 64, HID / 256, 2), 256, 0, stream>>>(x, wgb, part1);
  const int hn4 = (MROWS * HID) / 4;         // 2,097,152
  reduce2<<<hn4 / 256, 256, 0, stream>>>((float4*)part1, hn4);   // h = plane0

  // phase 2: layer 2 (pack w2 now that w1b' is dead)
  {
    const int waves = (DMODEL / 16) * (HID / 2);   // 48 * 1024 = 49152
    conv_pack<HID><<<waves / 4, 256, 0, stream>>>(w2, wgb, waves);
  }
  kan_gemm<HID, DMODEL, 4>
      <<<dim3(MROWS / 64, DMODEL / 256, 4), 256, 0, stream>>>(hbf, wgb, part2);
  const int rn4 = (MROWS * DMODEL) / 4;      // 786,432
  reduce4<<<rn4 / 256, 256, 0, stream>>>((const float4*)part2, (float4*)out, rn4);
}

// Round 13
// 454.519 us; speedup vs baseline: 1.2325x; 1.2325x over previous
//
#include <hip/hip_runtime.h>
#include <stdint.h>

typedef __attribute__((ext_vector_type(8))) short short8;
typedef __attribute__((ext_vector_type(4))) float f32x4;
typedef __attribute__((ext_vector_type(4))) int i32x4;

#define DMODEL 768
#define HID    2048
#define MROWS  4096   // 2*2048 tokens

// B-spline constants: h = (4-(-4))/(16-3) = 8/13
#define KINVH  (13.0f/8.0f)
#define KNOT0  (-4.0f - 3.0f*(8.0f/13.0f))

__device__ __forceinline__ unsigned short f2bf(float f) {
  unsigned int u = __float_as_uint(f);
  unsigned int r = (u + 0x7FFFu + ((u >> 16) & 1u)) >> 16;
  return (unsigned short)r;
}

// ---- weight f32 -> bf16, packed in MFMA-fragment order ----
// dst 16B-unit layout: [cb=col/16][kt2=k/32][q=l>>4][c16=l&15]; a B-fragment
// load (fixed cb,kt2) is lane-linear: addr = base + lane*16B.
template<int DIN>
__global__ void __launch_bounds__(256) conv_pack(const float* __restrict__ src,
                                                 unsigned short* __restrict__ dst,
                                                 int total_waves) {
  constexpr int NK2 = DIN / 2;               // number of 32-wide k halves
  int gw = blockIdx.x * 4 + (threadIdx.x >> 6);
  if (gw >= total_waves) return;
  int l   = threadIdx.x & 63;
  int cb  = gw / NK2;
  int kt2 = gw % NK2;
  int c16 = l & 15, q = l >> 4;
  int col = cb * 16 + c16;
  const float* s = src + ((size_t)col * DIN + kt2 * 2 + (q >> 1)) * 16 + (q & 1) * 8;
  float4 v0 = *(const float4*)s;
  float4 v1 = *(const float4*)(s + 4);
  short8 o;
  o[0] = (short)f2bf(v0.x); o[1] = (short)f2bf(v0.y);
  o[2] = (short)f2bf(v0.z); o[3] = (short)f2bf(v0.w);
  o[4] = (short)f2bf(v1.x); o[5] = (short)f2bf(v1.y);
  o[6] = (short)f2bf(v1.z); o[7] = (short)f2bf(v1.w);
  unsigned short* d = dst + (((size_t)cb * NK2 + kt2) * 64 + q * 16 + c16) * 8;
  *(short8*)d = o;
}

// ---- split-K=2 reduce, in place: p[i] = p[i] + p[i+n4] ----
__global__ void __launch_bounds__(256) reduce2(float4* __restrict__ p, int n4) {
  int i = blockIdx.x * 256 + threadIdx.x;
  if (i >= n4) return;
  float4 a = p[i], b = p[i + n4];
  float4 r;
  r.x = a.x + b.x; r.y = a.y + b.y; r.z = a.z + b.z; r.w = a.w + b.w;
  p[i] = r;
}

// ---- split-K=4 reduce: out[i] = sum over 4 planes ----
__global__ void __launch_bounds__(256) reduce4(const float4* __restrict__ p,
                                               float4* __restrict__ out, int n4) {
  int i = blockIdx.x * 256 + threadIdx.x;
  if (i >= n4) return;
  float4 a = p[i], b = p[i + n4], c = p[i + 2 * n4], d = p[i + 3 * n4];
  float4 r;
  r.x = a.x + b.x + c.x + d.x;
  r.y = a.y + b.y + c.y + d.y;
  r.z = a.z + b.z + c.z + d.z;
  r.w = a.w + b.w + c.w + d.w;
  out[i] = r;
}

// ---- fused basis + GEMM: A via LDS (8KB), B direct global->register ----
// C[n,o] = sum_{d,k} basis(X[n,d])_k * Wb'[o,k]
// Tile: BM=64 x BN=256, BK=64. 4 waves in 1x4; wave tile 64x64 (FM=FN=4).
// = r11 (510us winner) + register diet: per-kk A-frag reads (saves ~16 VGPR)
// and __launch_bounds__(256,4) so VGPR+AGPR <= 128 total/wave -> the HW wave
// budget (m69: halves at 128) gives 4 waves/SIMD instead of 2: residency
// 2 -> 4 blocks/CU, which is what hides the per-step serial chain.
template<int DIN, int DOUT, int SPLITK>
__global__ void __launch_bounds__(256, 4)
kan_gemm(const float* __restrict__ X, const unsigned short* __restrict__ Wb,
         float* __restrict__ Out) {
  constexpr int BM  = 64;
  constexpr int BN  = 256;
  constexpr int NK  = (DIN * 16) / 64;
  constexpr int NK2 = DIN / 2;
  constexpr int NKS = NK / SPLITK;
  constexpr int GX  = MROWS / BM;          // 64
  constexpr int GY  = DOUT / BN;
  constexpr int CPX = (GX * GY) / 8;       // blocks per XCD (nwg%8==0, bijective)
  __shared__ __align__(16) char smA[BM * 128];   // 64 rows x 64 bf16 (swizzled) = 8KB

  const int tid  = threadIdx.x;
  const int lane = tid & 63;
  const int wid  = tid >> 6;

  // XCD-chunked remap
  const int d    = blockIdx.x + blockIdx.y * GX;
  const int lf   = (d & 7) * CPX + (d >> 3);
  const int brow = (lf % GX) * BM;
  const int bcol = (lf / GX) * BN;
  const int kt0  = blockIdx.z * NKS;
  const int kt1  = kt0 + NKS;

  f32x4 acc[4][4];
#pragma unroll
  for (int m = 0; m < 4; ++m)
#pragma unroll
    for (int n = 0; n < 4; ++n) acc[m][n] = (f32x4){0.f, 0.f, 0.f, 0.f};

  // A-fragment LDS addressing (constant per lane)
  int a_base[4], a_sw[4];
#pragma unroll
  for (int m = 0; m < 4; ++m) {
    int row   = m * 16 + (lane & 15);
    a_base[m] = row * 128 + ((lane >> 4) * 16);
    a_sw[m]   = (row & 7) << 4;
  }

  // B-fragment pointers: frag n, lane-linear in packed layout
  const unsigned short* bp[4];
#pragma unroll
  for (int n = 0; n < 4; ++n)
    bp[n] = Wb + ((size_t)(bcol / 16 + wid * 4 + n) * NK2 + (size_t)kt0 * 2) * 512
               + lane * 8;

  const int br_ = tid >> 2;        // basis row
  const int bd_ = tid & 3;         // basis d-col within the 4-col step
  const float* xrow = X + (size_t)(brow + br_) * DIN + bd_;

  // ---- prologue: X(kt0) + B(kt0) in flight
  float xcur = xrow[(size_t)kt0 * 4];
  short8 bv[2][4];
#pragma unroll
  for (int n = 0; n < 4; ++n) {
    bv[0][n] = *(const short8*)(bp[n]);
    bv[1][n] = *(const short8*)(bp[n] + 512);
    bp[n] += 1024;
  }

  for (int kt = kt0; kt < kt1; ++kt) {
    __syncthreads();   // prev A-frag reads done; drains in-flight vmem (B/X landed)

    // ---- stage A: basis from prefetched xcur, scatter to swizzled LDS
    {
      float u  = (xcur - KNOT0) * KINVH;
      float uf = floorf(u);
      int   jj = (int)uf;
      float t  = u - uf;
      float t2 = t * t, t3 = t2 * t;
      float p0 = (1.0f / 6.0f) * (1.0f - 3.0f * t + 3.0f * t2 - t3);
      float p1 = (1.0f / 6.0f) * (4.0f - 6.0f * t2 + 3.0f * t3);
      float p2 = (1.0f / 6.0f) * (1.0f + 3.0f * t + 3.0f * t2 - 3.0f * t3);
      float p3 = (1.0f / 6.0f) * t3;

      int base = br_ * 128 + bd_ * 32;
      int sw   = (br_ & 7) << 4;
      *(i32x4*)(smA + (base ^ sw))        = (i32x4){0, 0, 0, 0};
      *(i32x4*)(smA + ((base + 16) ^ sw)) = (i32x4){0, 0, 0, 0};
      unsigned short q0 = f2bf(p0), q1 = f2bf(p1), q2 = f2bf(p2), q3 = f2bf(p3);
      int k0 = jj - 3;
      if ((unsigned)(k0 + 0) < 16u) *(unsigned short*)(smA + ((base + (k0 + 0) * 2) ^ sw)) = q0;
      if ((unsigned)(k0 + 1) < 16u) *(unsigned short*)(smA + ((base + (k0 + 1) * 2) ^ sw)) = q1;
      if ((unsigned)(k0 + 2) < 16u) *(unsigned short*)(smA + ((base + (k0 + 2) * 2) ^ sw)) = q2;
      if ((unsigned)(k0 + 3) < 16u) *(unsigned short*)(smA + ((base + (k0 + 3) * 2) ^ sw)) = q3;
    }

    // prefetch X for next step
    {
      int ktn = (kt + 1 < kt1) ? kt + 1 : kt;
      xcur = xrow[(size_t)ktn * 4];
    }

    __syncthreads();   // A-tile visible

    // ---- compute: per-kk A-frag reads (keeps only 4 A frags live)
#pragma unroll
    for (int kk = 0; kk < 2; ++kk) {
      short8 a[4];
#pragma unroll
      for (int m = 0; m < 4; ++m)
        a[m] = *(const short8*)(smA + ((a_base[m] + kk * 64) ^ a_sw[m]));
#pragma unroll
      for (int m = 0; m < 4; ++m)
#pragma unroll
        for (int n = 0; n < 4; ++n)
          acc[m][n] = __builtin_amdgcn_mfma_f32_16x16x32_bf16(a[m], bv[kk][n], acc[m][n], 0, 0, 0);
    }

    // issue next-step B loads into bv (WAR after MFMAs; drain at next barrier)
    if (kt + 1 < kt1) {
#pragma unroll
      for (int n = 0; n < 4; ++n) {
        bv[0][n] = *(const short8*)(bp[n]);
        bv[1][n] = *(const short8*)(bp[n] + 512);
        bp[n] += 1024;
      }
    }
  }

  // ---- epilogue: C/D layout col=lane&15, row=(lane>>4)*4+q
  float* outp = Out + (size_t)blockIdx.z * MROWS * DOUT;
#pragma unroll
  for (int m = 0; m < 4; ++m)
#pragma unroll
    for (int n = 0; n < 4; ++n)
#pragma unroll
      for (int q = 0; q < 4; ++q) {
        int grow = brow + m * 16 + (lane >> 4) * 4 + q;
        int gcol = bcol + wid * 64 + n * 16 + (lane & 15);
        outp[(size_t)grow * DOUT + gcol] = acc[m][n][q];
      }
}

extern "C" void kernel_launch(void* const* d_in, const int* in_sizes, int n_in,
                              void* d_out, int out_size, void* d_ws, size_t ws_size,
                              hipStream_t stream) {
  const float* x  = (const float*)d_in[0];   // (2,2048,768) f32 -> (4096,768)
  const float* w1 = (const float*)d_in[1];   // (2048,768,16) f32
  const float* w2 = (const float*)d_in[2];   // (768,2048,16) f32
  float* out = (float*)d_out;                // (4096,768) f32

  // ws timeline (128 MiB):
  //   [0, 48M)   : w1b' (phase 1), then w2b' (phase 2, after GEMM1)
  //   [48M, 80M) : GEMM1 partial plane 0 -> becomes h (f32) after reduce2
  //   [80M, 112M): GEMM1 partial plane 1 (dead after reduce2)
  //   [80M, 128M): GEMM2 partial planes 0..3 (overwrites plane 1)
  char* ws = (char*)d_ws;
  unsigned short* wgb   = (unsigned short*)ws;                  // 50,331,648 B
  float*          part1 = (float*)(ws + 50331648);              // 2 x 33,554,432 B
  float*          hbf   = part1;                                // alias: plane 0
  float*          part2 = (float*)(ws + 83886080);              // 4 x 12,582,912 B (end = 128MiB)

  // phase 1: layer 1
  {
    const int waves = (HID / 16) * (DMODEL / 2);   // 128 * 384 = 49152
    conv_pack<DMODEL><<<waves / 4, 256, 0, stream>>>(w1, wgb, waves);
  }
  kan_gemm<DMODEL, HID, 2>
      <<<dim3(MROWS / 64, HID / 256, 2), 256, 0, stream>>>(x, wgb, part1);
  const int hn4 = (MROWS * HID) / 4;         // 2,097,152
  reduce2<<<hn4 / 256, 256, 0, stream>>>((float4*)part1, hn4);   // h = plane0

  // phase 2: layer 2 (pack w2 now that w1b' is dead)
  {
    const int waves = (DMODEL / 16) * (HID / 2);   // 48 * 1024 = 49152
    conv_pack<HID><<<waves / 4, 256, 0, stream>>>(w2, wgb, waves);
  }
  kan_gemm<HID, DMODEL, 4>
      <<<dim3(MROWS / 64, DMODEL / 256, 4), 256, 0, stream>>>(hbf, wgb, part2);
  const int rn4 = (MROWS * DMODEL) / 4;      // 786,432
  reduce4<<<rn4 / 256, 256, 0, stream>>>((const float4*)part2, (float4*)out, rn4);
}

// Round 14
// 454.433 us; speedup vs baseline: 1.2327x; 1.0002x over previous
//
#include <hip/hip_runtime.h>
#include <stdint.h>

typedef __attribute__((ext_vector_type(8))) short short8;
typedef __attribute__((ext_vector_type(4))) float f32x4;
typedef __attribute__((ext_vector_type(4))) int i32x4;

#define DMODEL 768
#define HID    2048
#define MROWS  4096   // 2*2048 tokens

// B-spline constants: h = (4-(-4))/(16-3) = 8/13
#define KINVH  (13.0f/8.0f)
#define KNOT0  (-4.0f - 3.0f*(8.0f/13.0f))

// Relaxed barrier: LDS-ordering only (lgkmcnt), NO vmcnt drain — lets the
// in-flight B/X global loads span the barrier (their consumers get the
// compiler's automatic vmcnt wait). sched_barrier(0) per rule #18.
#define BAR_LDS() do { asm volatile("s_waitcnt lgkmcnt(0)" ::: "memory"); \
                       __builtin_amdgcn_s_barrier(); \
                       __builtin_amdgcn_sched_barrier(0); } while (0)

__device__ __forceinline__ unsigned short f2bf(float f) {
  unsigned int u = __float_as_uint(f);
  unsigned int r = (u + 0x7FFFu + ((u >> 16) & 1u)) >> 16;
  return (unsigned short)r;
}

// ---- weight f32 -> bf16, packed in MFMA-fragment order ----
// dst 16B-unit layout: [cb=col/16][kt2=k/32][q=l>>4][c16=l&15]; a B-fragment
// load (fixed cb,kt2) is lane-linear: addr = base + lane*16B.
template<int DIN>
__global__ void __launch_bounds__(256) conv_pack(const float* __restrict__ src,
                                                 unsigned short* __restrict__ dst,
                                                 int total_waves) {
  constexpr int NK2 = DIN / 2;               // number of 32-wide k halves
  int gw = blockIdx.x * 4 + (threadIdx.x >> 6);
  if (gw >= total_waves) return;
  int l   = threadIdx.x & 63;
  int cb  = gw / NK2;
  int kt2 = gw % NK2;
  int c16 = l & 15, q = l >> 4;
  int col = cb * 16 + c16;
  const float* s = src + ((size_t)col * DIN + kt2 * 2 + (q >> 1)) * 16 + (q & 1) * 8;
  float4 v0 = *(const float4*)s;
  float4 v1 = *(const float4*)(s + 4);
  short8 o;
  o[0] = (short)f2bf(v0.x); o[1] = (short)f2bf(v0.y);
  o[2] = (short)f2bf(v0.z); o[3] = (short)f2bf(v0.w);
  o[4] = (short)f2bf(v1.x); o[5] = (short)f2bf(v1.y);
  o[6] = (short)f2bf(v1.z); o[7] = (short)f2bf(v1.w);
  unsigned short* d = dst + (((size_t)cb * NK2 + kt2) * 64 + q * 16 + c16) * 8;
  *(short8*)d = o;
}

// ---- split-K=4 reduce: out[i] = sum over 4 planes ----
__global__ void __launch_bounds__(256) reduce4(const float4* __restrict__ p,
                                               float4* __restrict__ out, int n4) {
  int i = blockIdx.x * 256 + threadIdx.x;
  if (i >= n4) return;
  float4 a = p[i], b = p[i + n4], c = p[i + 2 * n4], d = p[i + 3 * n4];
  float4 r;
  r.x = a.x + b.x + c.x + d.x;
  r.y = a.y + b.y + c.y + d.y;
  r.z = a.z + b.z + c.z + d.z;
  r.w = a.w + b.w + c.w + d.w;
  out[i] = r;
}

// ---- fused basis + GEMM: A via LDS (8KB), B direct global->register ----
// C[n,o] = sum_{d,k} basis(X[n,d])_k * Wb'[o,k]
// Tile: BM=64 x BN=256, BK=64. 4 waves in 1x4; wave tile 64x64 (FM=FN=4).
// r13 winner (64+64 regs -> 4 waves/SIMD) + relaxed barriers: the per-step
// vmcnt(0) drain at __syncthreads was serializing the B-load round trip
// (issued at step end, drained immediately at next step top). BAR_LDS keeps
// the loads in flight; their vmcnt wait lands just before the MFMA uses,
// hidden under basis VALU. SUM2: GEMM2 sums the two GEMM1 partial planes
// on load (folds reduce2 away).
template<int DIN, int DOUT, int SPLITK, bool SUM2>
__global__ void __launch_bounds__(256, 4)
kan_gemm(const float* __restrict__ X, const unsigned short* __restrict__ Wb,
         float* __restrict__ Out) {
  constexpr int BM  = 64;
  constexpr int BN  = 256;
  constexpr int NK  = (DIN * 16) / 64;
  constexpr int NK2 = DIN / 2;
  constexpr int NKS = NK / SPLITK;
  constexpr int GX  = MROWS / BM;          // 64
  constexpr int GY  = DOUT / BN;
  constexpr int CPX = (GX * GY) / 8;       // blocks per XCD (nwg%8==0, bijective)
  __shared__ __align__(16) char smA[BM * 128];   // 64 rows x 64 bf16 (swizzled) = 8KB

  const int tid  = threadIdx.x;
  const int lane = tid & 63;
  const int wid  = tid >> 6;

  // XCD-chunked remap
  const int d    = blockIdx.x + blockIdx.y * GX;
  const int lf   = (d & 7) * CPX + (d >> 3);
  const int brow = (lf % GX) * BM;
  const int bcol = (lf / GX) * BN;
  const int kt0  = blockIdx.z * NKS;
  const int kt1  = kt0 + NKS;

  f32x4 acc[4][4];
#pragma unroll
  for (int m = 0; m < 4; ++m)
#pragma unroll
    for (int n = 0; n < 4; ++n) acc[m][n] = (f32x4){0.f, 0.f, 0.f, 0.f};

  // A-fragment LDS addressing (constant per lane)
  int a_base[4], a_sw[4];
#pragma unroll
  for (int m = 0; m < 4; ++m) {
    int row   = m * 16 + (lane & 15);
    a_base[m] = row * 128 + ((lane >> 4) * 16);
    a_sw[m]   = (row & 7) << 4;
  }

  // B-fragment pointers: frag n, lane-linear in packed layout
  const unsigned short* bp[4];
#pragma unroll
  for (int n = 0; n < 4; ++n)
    bp[n] = Wb + ((size_t)(bcol / 16 + wid * 4 + n) * NK2 + (size_t)kt0 * 2) * 512
               + lane * 8;

  const int br_ = tid >> 2;        // basis row
  const int bd_ = tid & 3;         // basis d-col within the 4-col step
  const float* xrow0 = X + (size_t)(brow + br_) * DIN + bd_;
  const float* xrow1 = xrow0 + (SUM2 ? (size_t)MROWS * DIN : 0);

  // ---- prologue: X(kt0) + B(kt0) in flight
  float xa = xrow0[(size_t)kt0 * 4];
  float xb = SUM2 ? xrow1[(size_t)kt0 * 4] : 0.f;
  short8 bv[2][4];
#pragma unroll
  for (int n = 0; n < 4; ++n) {
    bv[0][n] = *(const short8*)(bp[n]);
    bv[1][n] = *(const short8*)(bp[n] + 512);
    bp[n] += 1024;
  }

  for (int kt = kt0; kt < kt1; ++kt) {
    BAR_LDS();   // prev A-frag reads done (LDS only; B/X loads stay in flight)

    // ---- stage A: basis from prefetched x, scatter to swizzled LDS
    {
      float xv = SUM2 ? (xa + xb) : xa;
      float u  = (xv - KNOT0) * KINVH;
      float uf = floorf(u);
      int   jj = (int)uf;
      float t  = u - uf;
      float t2 = t * t, t3 = t2 * t;
      float p0 = (1.0f / 6.0f) * (1.0f - 3.0f * t + 3.0f * t2 - t3);
      float p1 = (1.0f / 6.0f) * (4.0f - 6.0f * t2 + 3.0f * t3);
      float p2 = (1.0f / 6.0f) * (1.0f + 3.0f * t + 3.0f * t2 - 3.0f * t3);
      float p3 = (1.0f / 6.0f) * t3;

      int base = br_ * 128 + bd_ * 32;
      int sw   = (br_ & 7) << 4;
      *(i32x4*)(smA + (base ^ sw))        = (i32x4){0, 0, 0, 0};
      *(i32x4*)(smA + ((base + 16) ^ sw)) = (i32x4){0, 0, 0, 0};
      unsigned short q0 = f2bf(p0), q1 = f2bf(p1), q2 = f2bf(p2), q3 = f2bf(p3);
      int k0 = jj - 3;
      if ((unsigned)(k0 + 0) < 16u) *(unsigned short*)(smA + ((base + (k0 + 0) * 2) ^ sw)) = q0;
      if ((unsigned)(k0 + 1) < 16u) *(unsigned short*)(smA + ((base + (k0 + 1) * 2) ^ sw)) = q1;
      if ((unsigned)(k0 + 2) < 16u) *(unsigned short*)(smA + ((base + (k0 + 2) * 2) ^ sw)) = q2;
      if ((unsigned)(k0 + 3) < 16u) *(unsigned short*)(smA + ((base + (k0 + 3) * 2) ^ sw)) = q3;
    }

    // prefetch X for next step
    {
      int ktn = (kt + 1 < kt1) ? kt + 1 : kt;
      xa = xrow0[(size_t)ktn * 4];
      if (SUM2) xb = xrow1[(size_t)ktn * 4];
    }

    BAR_LDS();   // A-tile visible (ds_writes flushed; vmem still in flight)

    // ---- compute: per-kk A-frag reads (keeps only 4 A frags live)
#pragma unroll
    for (int kk = 0; kk < 2; ++kk) {
      short8 a[4];
#pragma unroll
      for (int m = 0; m < 4; ++m)
        a[m] = *(const short8*)(smA + ((a_base[m] + kk * 64) ^ a_sw[m]));
#pragma unroll
      for (int m = 0; m < 4; ++m)
#pragma unroll
        for (int n = 0; n < 4; ++n)
          acc[m][n] = __builtin_amdgcn_mfma_f32_16x16x32_bf16(a[m], bv[kk][n], acc[m][n], 0, 0, 0);
    }

    // issue next-step B loads into bv (WAR-safe after MFMA issue; latency
    // now spans the next barrier into the next basis phase)
    if (kt + 1 < kt1) {
#pragma unroll
      for (int n = 0; n < 4; ++n) {
        bv[0][n] = *(const short8*)(bp[n]);
        bv[1][n] = *(const short8*)(bp[n] + 512);
        bp[n] += 1024;
      }
    }
  }

  // ---- epilogue: C/D layout col=lane&15, row=(lane>>4)*4+q
  float* outp = Out + (size_t)blockIdx.z * MROWS * DOUT;
#pragma unroll
  for (int m = 0; m < 4; ++m)
#pragma unroll
    for (int n = 0; n < 4; ++n)
#pragma unroll
      for (int q = 0; q < 4; ++q) {
        int grow = brow + m * 16 + (lane >> 4) * 4 + q;
        int gcol = bcol + wid * 64 + n * 16 + (lane & 15);
        outp[(size_t)grow * DOUT + gcol] = acc[m][n][q];
      }
}

extern "C" void kernel_launch(void* const* d_in, const int* in_sizes, int n_in,
                              void* d_out, int out_size, void* d_ws, size_t ws_size,
                              hipStream_t stream) {
  const float* x  = (const float*)d_in[0];   // (2,2048,768) f32 -> (4096,768)
  const float* w1 = (const float*)d_in[1];   // (2048,768,16) f32
  const float* w2 = (const float*)d_in[2];   // (768,2048,16) f32
  float* out = (float*)d_out;                // (4096,768) f32

  // ws timeline (128 MiB):
  //   [0, 48M)   : w1b' (phase 1), then w2b' (phase 2, after GEMM1)
  //   [48M, 80M) : GEMM1 partial plane 0  } summed on load by GEMM2 (SUM2)
  //   [80M, 112M): GEMM1 partial plane 1  }
  //   [80M, 128M): GEMM2 partial planes 0..3 — WAIT: would overlap plane 1!
  //   -> GEMM2 partials go to [48M, 96M)?? No: plane0/1 both live during GEMM2.
  //   Fix: GEMM2 partials at [96M, 128M) is only 32M (<48M needed).
  //   Use: planes live [48M,112M); GEMM2 partials 4 x 12M = 48M at [0M,48M)?
  //   w2b' also lives at [0,48M). -> Put GEMM2 partials at [112M,128M)=16M? No.
  //   Resolution: GEMM2 writes partials over plane data it has ALREADY consumed
  //   is unsafe (blocks consume asynchronously). Instead keep reduce-free only
  //   for plane1: GEMM2 partials at [80M,128M) would clobber plane1 mid-read.
  //   -> Safe layout: move GEMM1 planes to [48M,112M), GEMM2 partials [112M,128M)
  //   too small. FINAL: keep SUM2 but give GEMM2 partials the w1b' slot after
  //   repacking w2 into [112M,128M)? 48M needed, 16M available. -> Abandon that;
  //   simplest safe option: w2b' packs into [0,48M) (over dead w1b'), GEMM1
  //   planes stay [48M,112M), GEMM2 partials reuse [0,48M)?? w2b' is live.
  //   => TRUE resolution used below: GEMM2 uses SPLITK=4 with ATOMIC-FREE
  //   partial planes of 12M each placed in the 16M tail [112M,128M) is
  //   impossible; so GEMM2 keeps SPLITK=2 planes (2x12M=24M)? Occupancy drops.
  //   DECISION: revert to explicit reduce2 (planes freed before GEMM2) — keep
  //   the barrier fix only, which is the main lever this round.
  char* ws = (char*)d_ws;
  unsigned short* wgb   = (unsigned short*)ws;                  // 50,331,648 B
  float*          part1 = (float*)(ws + 50331648);              // 2 x 33,554,432 B
  float*          hbf   = part1;                                // alias: plane 0
  float*          part2 = (float*)(ws + 83886080);              // 4 x 12,582,912 B (end = 128MiB)

  // phase 1: layer 1
  {
    const int waves = (HID / 16) * (DMODEL / 2);   // 128 * 384 = 49152
    conv_pack<DMODEL><<<waves / 4, 256, 0, stream>>>(w1, wgb, waves);
  }
  kan_gemm<DMODEL, HID, 2, false>
      <<<dim3(MROWS / 64, HID / 256, 2), 256, 0, stream>>>(x, wgb, part1);

  // phase 2: layer 2 — SUM2 folds the plane0+plane1 add into the basis load.
  // Plane liveness: planes at [48M,112M) are read-only inputs of GEMM2; GEMM2
  // partials (4 x 12M = 48M) CANNOT overlap them, so they go to... the only
  // free region is [0,48M) which holds w2b'. Therefore SUM2 requires GEMM2
  // output to go elsewhere: we write GEMM2 partials into [80M,128M) ONLY IF
  // plane1 is dead — it is NOT under SUM2. => Use out-of-place trick: GEMM2
  // SPLITK=4 partials are 48M; region [48M,80M) (plane0) is also live.
  // No legal layout exists with SUM2 + SPLITK=4 in 128M. So: small in-place
  // reduce2 stays, SUM2 disabled. (Kernel supports it for future use.)
  {
    const int hn4 = (MROWS * HID) / 4;
    // in-place reduce2: p[i] += p[i+n4]
    // reuse reduce4 infrastructure via a tiny lambda-kernel is overkill;
    // do it with a dedicated kernel below.
    extern __global__ void reduce2_k(float4*, int);
  }
  // (reduce2 defined after kernel_launch would not link; do it inline here)
  {
    struct R2 {
      static __global__ void __launch_bounds__(256) run(float4* p, int n4) {
        int i = blockIdx.x * 256 + threadIdx.x;
        if (i >= n4) return;
        float4 a = p[i], b = p[i + n4];
        float4 r; r.x = a.x + b.x; r.y = a.y + b.y; r.z = a.z + b.z; r.w = a.w + b.w;
        p[i] = r;
      }
    };
    const int hn4 = (MROWS * HID) / 4;         // 2,097,152
    R2::run<<<hn4 / 256, 256, 0, stream>>>((float4*)part1, hn4);
  }
  {
    const int waves = (DMODEL / 16) * (HID / 2);   // 48 * 1024 = 49152
    conv_pack<HID><<<waves / 4, 256, 0, stream>>>(w2, wgb, waves);
  }
  kan_gemm<HID, DMODEL, 4, false>
      <<<dim3(MROWS / 64, DMODEL / 256, 4), 256, 0, stream>>>(hbf, wgb, part2);
  const int rn4 = (MROWS * DMODEL) / 4;      // 786,432
  reduce4<<<rn4 / 256, 256, 0, stream>>>((const float4*)part2, (float4*)out, rn4);
}